// Round 3
// baseline (147.186 us; speedup 1.0000x reference)
//
#include <hip/hip_runtime.h>

#define H 256
#define NB 2048
#define BATCH 8
#define NSPLIT 8
#define KSPAN (NB / NSPLIT)   // 256 keys per split
#define NITER (KSPAN / 64)    // 4 double-buffered 64-key tiles

typedef unsigned short u16;
using bf16x8 = __attribute__((ext_vector_type(8))) __bf16;
using f32x4  = __attribute__((ext_vector_type(4))) float;

typedef const __attribute__((address_space(1))) void gv_t;
typedef __attribute__((address_space(3))) void lv_t;

// async 16B-per-lane global->LDS: lds dst is wave-uniform base, lane i lands at base+16*i
__device__ __forceinline__ void gl_lds16(const void* g, void* l) {
    __builtin_amdgcn_global_load_lds((gv_t*)g, (lv_t*)l, 16, 0, 0);
}

#define MFMA(a, b, c) __builtin_amdgcn_mfma_f32_16x16x32_bf16(a, b, c, 0, 0, 0)

__device__ __forceinline__ u16 f2bf(float f) {
    union { float f; unsigned u; } v; v.f = f;
    unsigned r = v.u + 0x7fffu + ((v.u >> 16) & 1u);  // RNE
    return (u16)(r >> 16);
}

__device__ __forceinline__ bf16x8 cvt8(const float* p) {
    float4 f0 = *(const float4*)p;
    float4 f1 = *(const float4*)(p + 4);
    union { bf16x8 v; u16 u[8]; } r;
    r.u[0] = f2bf(f0.x); r.u[1] = f2bf(f0.y); r.u[2] = f2bf(f0.z); r.u[3] = f2bf(f0.w);
    r.u[4] = f2bf(f1.x); r.u[5] = f2bf(f1.y); r.u[6] = f2bf(f1.z); r.u[7] = f2bf(f1.w);
    return r.v;
}

// ---- K1 prep (fused wprep + aT-gemm + split-counter zero):
//   blocks 0..255:  wvw[f] = Wv[f,:]·Ww, kbv[f] = Wk[f,:]·bq; block 0 also cc = bv·Ww
//                   and zeroes the 64 split counters (workspace is re-poisoned
//                   every iteration, so cnt MUST be re-zeroed in-stream).
//   blocks 256..263: aT[f][e] = bf16((Wk_bf[f,:]·Wq_bf[e,:])/16), weights
//   converted to bf16 in-kernel. ----
__global__ __launch_bounds__(256) void prep_kernel(
        const float* __restrict__ Wq, const float* __restrict__ Wk,
        const float* __restrict__ Wv, const float* __restrict__ Ww,
        const float* __restrict__ bq, const float* __restrict__ bv,
        u16* __restrict__ aTb, float* __restrict__ wvw,
        float* __restrict__ kbv, float* __restrict__ ccp, int* __restrict__ cnt) {
    __shared__ u16 bt[16384];   // 32KB fragment-major (gemm blocks only)
    int id = blockIdx.x, t = threadIdx.x;

    if (id < 256) {   // reduction blocks
        int f = id;
        if (id == 0 && t < 64) cnt[t] = 0;   // cross-kernel visibility via dispatch-boundary flush
        float p = Wv[f * H + t] * Ww[t];
        float r = Wk[f * H + t] * bq[t];
        float c = (id == 0) ? bv[t] * Ww[t] : 0.f;
        for (int o = 32; o; o >>= 1) {
            p += __shfl_xor(p, o); r += __shfl_xor(r, o); c += __shfl_xor(c, o);
        }
        __shared__ float redp[4], redr[4], redc[4];
        int w = t >> 6, lane = t & 63;
        if (lane == 0) { redp[w] = p; redr[w] = r; redc[w] = c; }
        __syncthreads();
        if (t == 0) {
            wvw[f] = redp[0] + redp[1] + redp[2] + redp[3];
            kbv[f] = redr[0] + redr[1] + redr[2] + redr[3];
            if (f == 0) ccp[0] = redc[0] + redc[1] + redc[2] + redc[3];
        }
        return;
    }

    // gemm blocks: gid 0..7 -> 128x64 tile of aT (256x256), K=256
    int gid = id - 256;
    int mb = (gid >> 2) * 128, nb = (gid & 3) * 64;
    int w = t >> 6, lane = t & 63, l15 = lane & 15, quad = lane >> 4;

    {   // stage B = bf16(Wq rows nb..nb+63), fragment-major
        const float* src = Wq + (nb + w * 16 + l15) * H + quad * 8;
        #pragma unroll
        for (int ks = 0; ks < 8; ++ks)
            *(bf16x8*)(bt + (w * 8 + ks) * 512 + lane * 8) = cvt8(src + ks * 32);
    }

    bf16x8 a[2][8];
    #pragma unroll
    for (int mi = 0; mi < 2; ++mi) {
        const float* ab = Wk + (mb + w * 32 + mi * 16 + l15) * H + quad * 8;
        #pragma unroll
        for (int ks = 0; ks < 8; ++ks) a[mi][ks] = cvt8(ab + ks * 32);
    }
    __syncthreads();

    f32x4 acc[2][4] = {};
    #pragma unroll
    for (int ks = 0; ks < 8; ++ks)
        #pragma unroll
        for (int tt = 0; tt < 4; ++tt) {
            bf16x8 b = *(const bf16x8*)(bt + ((tt * 8 + ks) * 64 + lane) * 8);
            acc[0][tt] = MFMA(a[0][ks], b, acc[0][tt]);
            acc[1][tt] = MFMA(a[1][ks], b, acc[1][tt]);
        }

    #pragma unroll
    for (int mi = 0; mi < 2; ++mi) {
        int m = mb + w * 32 + mi * 16 + quad * 4;
        #pragma unroll
        for (int tt = 0; tt < 4; ++tt) {
            int n = nb + tt * 16 + l15;
            #pragma unroll
            for (int r2 = 0; r2 < 4; ++r2)
                aTb[(m + r2) * H + n] = f2bf(acc[mi][tt][r2] * 0.0625f);
        }
    }
}

// ---- K2 xt (fused cvtu + T-gemm, NO redundant x reads):
//   512 blocks, each owns 32 rows x ALL 256 cols of T. Each x row is read by
//   exactly one block (16 MB HBM total). B = aT streamed from global straight
//   into registers (128 KB, L2-hot) — no LDS, no barrier. Wave w covers
//   n-tiles w*4..w*4+3 with B-fragment reuse 2 (mi=0,1). Accumulators are
//   per-t locals (no runtime-indexed register arrays -> no scratch).
//   Wave 0 additionally writes xbf + uee (identical f2bf bits to old cvtu). ----
__global__ __launch_bounds__(256) void xt_kernel(
        const float* __restrict__ x, const u16* __restrict__ aTb,
        const float* __restrict__ wvw, const float* __restrict__ kbv,
        const float* __restrict__ ccp,
        u16* __restrict__ xbf, float2* __restrict__ uee, u16* __restrict__ Tbf) {
    int id = blockIdx.x, tid = threadIdx.x;
    int w = tid >> 6, lane = tid & 63, l15 = lane & 15, quad = lane >> 4;
    int rb = id * 32;   // this block's 32 rows

    // A: convert the 32 rows to bf16 fragments; uee dot partials ride along
    bf16x8 a[2][8];
    float s[2] = {0.f, 0.f}, d[2] = {0.f, 0.f};
    #pragma unroll
    for (int ks = 0; ks < 8; ++ks) {
        const float* wp = wvw + ks * 32 + quad * 8;
        const float* kp = kbv + ks * 32 + quad * 8;
        float4 w0 = *(const float4*)wp, w1 = *(const float4*)(wp + 4);
        float4 k0 = *(const float4*)kp, k1 = *(const float4*)(kp + 4);
        #pragma unroll
        for (int mi = 0; mi < 2; ++mi) {
            const float* xr = x + (size_t)(rb + mi * 16 + l15) * H + ks * 32 + quad * 8;
            float4 f0 = *(const float4*)xr;
            float4 f1 = *(const float4*)(xr + 4);
            union { bf16x8 v; u16 u[8]; } r;
            r.u[0] = f2bf(f0.x); r.u[1] = f2bf(f0.y); r.u[2] = f2bf(f0.z); r.u[3] = f2bf(f0.w);
            r.u[4] = f2bf(f1.x); r.u[5] = f2bf(f1.y); r.u[6] = f2bf(f1.z); r.u[7] = f2bf(f1.w);
            a[mi][ks] = r.v;
            s[mi] += f0.x * w0.x + f0.y * w0.y + f0.z * w0.z + f0.w * w0.w
                   + f1.x * w1.x + f1.y * w1.y + f1.z * w1.z + f1.w * w1.w;
            d[mi] += f0.x * k0.x + f0.y * k0.y + f0.z * k0.z + f0.w * k0.w
                   + f1.x * k1.x + f1.y * k1.y + f1.z * k1.z + f1.w * k1.w;
        }
    }

    if (w == 0) {   // wave 0 owns the xbf + uee writes for all 32 rows
        #pragma unroll
        for (int mi = 0; mi < 2; ++mi) {
            u16* xo = xbf + (size_t)(rb + mi * 16 + l15) * H + quad * 8;
            #pragma unroll
            for (int ks = 0; ks < 8; ++ks)
                *(bf16x8*)(xo + ks * 32) = a[mi][ks];
        }
        float cc = ccp[0];
        #pragma unroll
        for (int mi = 0; mi < 2; ++mi) {
            float ss = s[mi] + __shfl_xor(s[mi], 16); ss += __shfl_xor(ss, 32);
            float dd = d[mi] + __shfl_xor(d[mi], 16); dd += __shfl_xor(dd, 32);
            if (quad == 0) {
                float e = __expf(dd * 0.0625f);
                uee[rb + mi * 16 + l15] = make_float2(e * (ss + cc), e);
            }
        }
    }

    // B-streamed GEMM: 4 n-tiles per wave, acc finalized & stored per tile
    #pragma unroll 1
    for (int t = 0; t < 4; ++t) {
        int n = (w * 4 + t) * 16 + l15;
        const u16* bb = aTb + n * H + quad * 8;
        bf16x8 bfr[8];
        #pragma unroll
        for (int ks = 0; ks < 8; ++ks) bfr[ks] = *(const bf16x8*)(bb + ks * 32);
        f32x4 acc0 = {}, acc1 = {};
        #pragma unroll
        for (int ks = 0; ks < 8; ++ks) {
            acc0 = MFMA(a[0][ks], bfr[ks], acc0);
            acc1 = MFMA(a[1][ks], bfr[ks], acc1);
        }
        #pragma unroll
        for (int r2 = 0; r2 < 4; ++r2) {
            Tbf[(size_t)(rb + quad * 4 + r2) * H + n]      = f2bf(acc0[r2]);
            Tbf[(size_t)(rb + 16 + quad * 4 + r2) * H + n] = f2bf(acc1[r2]);
        }
    }
}

// ---- K3 attention + fused finalize:
//      logit(n,m) = T[n]·x[m]; num += e^logit·(e·u)_m, den += e^logit·e_m.
//      64-key double-buffered tiles, t-outer/ks-inner, setprio around MFMA.
//      Split-K finalize: each (b,qc) group's 8 sp-blocks write partials, then
//      threadfence + atomicAdd(cnt); the 8th block fences, re-reads all
//      partials and writes out directly (standard last-block pattern).
//      Grid 512 = 2 blocks/CU; b in low 3 bits pins batch b -> XCD b. ----
__global__ __launch_bounds__(256, 2) void attn_kernel(
        const u16* __restrict__ T, const u16* __restrict__ xbf,
        const float2* __restrict__ uee, const float* __restrict__ bw,
        float* __restrict__ pnum, float* __restrict__ pden,
        int* __restrict__ cnt, float* __restrict__ out) {
    __shared__ u16 kt[32768];   // 2 x 32KB fragment-major 64-key tiles
    __shared__ int lastf;
    int tid = threadIdx.x;
    int id = blockIdx.x;
    int b = id & 7, rest = id >> 3;
    int qc = rest & 7, sp = rest >> 3;
    int w = tid >> 6, lane = tid & 63, l15 = lane & 15, quad = lane >> 4;
    int qb = qc * 256;

    // resident A fragments: 64 q-rows per wave (4 x 16)
    bf16x8 aq[4][8];
    {
        const u16* qbase = T + (size_t)(b * NB + qb + w * 64 + l15) * H + quad * 8;
        #pragma unroll
        for (int mi = 0; mi < 4; ++mi)
            #pragma unroll
            for (int ks = 0; ks < 8; ++ks)
                aq[mi][ks] = *(const bf16x8*)(qbase + mi * 16 * H + ks * 32);
    }

    const u16* xb = xbf + (size_t)b * NB * H;
    const float2* uep = uee + (size_t)b * NB;
    const int kb0 = sp * KSPAN;

    // wave w stages t-group w (16 keys, 8 ks-chunks of 1KB) of each 64-key tile
    const u16* gsrc = xb + (size_t)(kb0 + w * 16 + l15) * H + quad * 8;
    #pragma unroll
    for (int j = 0; j < 8; ++j)
        gl_lds16(gsrc + j * 32, kt + (w * 8 + j) * 512);
    __syncthreads();

    float ls[4][4] = {}, as_[4][4] = {};

    #pragma unroll 1
    for (int h = 0; h < NITER; ++h) {
        const u16* ktc = kt + (h & 1) * 16384;
        if (h + 1 < NITER) {   // stage next 64-key tile into the other buffer
            u16* dst = kt + ((h & 1) ^ 1) * 16384;
            const u16* g2 = gsrc + (size_t)(h + 1) * 64 * H;
            #pragma unroll
            for (int j = 0; j < 8; ++j)
                gl_lds16(g2 + j * 32, dst + (w * 8 + j) * 512);
        }
        int kb64 = kb0 + h * 64;
        float2 uv[4];
        #pragma unroll
        for (int t = 0; t < 4; ++t) uv[t] = uep[kb64 + t * 16 + l15];

        #pragma unroll
        for (int t = 0; t < 4; ++t) {
            f32x4 acc[4] = {};
            __builtin_amdgcn_s_setprio(1);
            #pragma unroll
            for (int ks = 0; ks < 8; ++ks) {
                bf16x8 bfr = *(const bf16x8*)(ktc + ((t * 8 + ks) * 64 + lane) * 8);
                acc[0] = MFMA(aq[0][ks], bfr, acc[0]);
                acc[1] = MFMA(aq[1][ks], bfr, acc[1]);
                acc[2] = MFMA(aq[2][ks], bfr, acc[2]);
                acc[3] = MFMA(aq[3][ks], bfr, acc[3]);
            }
            __builtin_amdgcn_s_setprio(0);
            #pragma unroll
            for (int mi = 0; mi < 4; ++mi)
                #pragma unroll
                for (int r = 0; r < 4; ++r) {
                    float p = __expf(acc[mi][r]);
                    as_[mi][r] += p * uv[t].x;
                    ls[mi][r]  += p * uv[t].y;
                }
        }
        __syncthreads();
    }

    // reduce over the 16 key-columns (l15)
    #pragma unroll
    for (int mi = 0; mi < 4; ++mi)
        #pragma unroll
        for (int r = 0; r < 4; ++r)
            for (int o = 1; o < 16; o <<= 1) {
                ls[mi][r]  += __shfl_xor(ls[mi][r], o);
                as_[mi][r] += __shfl_xor(as_[mi][r], o);
            }

    if (l15 == 0) {
        size_t base = (size_t)(sp * BATCH + b) * NB + qb + w * 64 + quad * 4;
        #pragma unroll
        for (int mi = 0; mi < 4; ++mi)
            #pragma unroll
            for (int r = 0; r < 4; ++r) {
                pnum[base + mi * 16 + r] = as_[mi][r];
                pden[base + mi * 16 + r] = ls[mi][r];
            }
    }

    // ---- fused finalize (last sp-block per (b,qc)) ----
    __syncthreads();   // drains this block's partial stores (vmcnt0 before barrier)
    if (tid == 0) {
        __threadfence();                                   // release: L2 writeback
        int old = atomicAdd(cnt + (b * 8 + qc), 1);
        lastf = (old == NSPLIT - 1) ? 1 : 0;
    }
    __syncthreads();
    if (lastf) {
        __threadfence();                                   // acquire: invalidate stale lines
        int row = qb + tid;                                // one row per thread
        float num = 0.f, den = 0.f;
        #pragma unroll
        for (int s2 = 0; s2 < NSPLIT; ++s2) {
            num += pnum[(size_t)(s2 * BATCH + b) * NB + row];
            den += pden[(size_t)(s2 * BATCH + b) * NB + row];
        }
        out[(size_t)b * NB + row] = num / den + bw[0];
    }
}

extern "C" void kernel_launch(void* const* d_in, const int* in_sizes, int n_in,
                              void* d_out, int out_size, void* d_ws, size_t ws_size,
                              hipStream_t stream) {
    (void)in_sizes; (void)n_in; (void)out_size; (void)ws_size;
    const float* x  = (const float*)d_in[0];
    const float* Wq = (const float*)d_in[1];
    const float* bq = (const float*)d_in[2];
    const float* Wk = (const float*)d_in[3];
    const float* bk = (const float*)d_in[4];  (void)bk;  // cancels in softmax
    const float* Wv = (const float*)d_in[5];
    const float* bv = (const float*)d_in[6];
    const float* Ww = (const float*)d_in[7];
    const float* bw = (const float*)d_in[8];
    float* out = (float*)d_out;

    u16* xbf = (u16*)d_ws;                     // 4194304 u16 (8 MB)
    u16* Tbf = xbf + 4194304;                  // 4194304 u16 (8 MB)
    u16* aTb = Tbf + 4194304;                  // 65536 u16
    float* wvw = (float*)(aTb + 65536);        // 256 f32
    float* kbv = wvw + 256;                    // 256 f32
    float* ccp = kbv + 256;                    // 4 f32 (1 used, keeps 8B align)
    float2* uee = (float2*)(ccp + 4);          // 16384 float2
    float* pnum = (float*)(uee + 16384);       // NSPLIT*16384 f32
    float* pden = pnum + NSPLIT * BATCH * NB;  // NSPLIT*16384 f32
    int* cnt = (int*)(pden + NSPLIT * BATCH * NB);  // 64 int

    hipLaunchKernelGGL(prep_kernel, dim3(264), dim3(256), 0, stream,
                       Wq, Wk, Wv, Ww, bq, bv, aTb, wvw, kbv, ccp, cnt);
    hipLaunchKernelGGL(xt_kernel, dim3(512), dim3(256), 0, stream,
                       x, aTb, wvw, kbv, ccp, xbf, uee, Tbf);
    hipLaunchKernelGGL(attn_kernel, dim3(8 * 8 * NSPLIT), dim3(256), 0, stream,
                       Tbf, xbf, uee, bw, pnum, pden, cnt, out);
}

// Round 4
// 139.287 us; speedup vs baseline: 1.0567x; 1.0567x over previous
//
#include <hip/hip_runtime.h>

#define H 256
#define NB 2048
#define BATCH 8
#define NSPLIT 8
#define KSPAN (NB / NSPLIT)   // 256 keys per split
#define NITER (KSPAN / 64)    // 4 double-buffered 64-key tiles

typedef unsigned short u16;
using bf16x8 = __attribute__((ext_vector_type(8))) __bf16;
using f32x4  = __attribute__((ext_vector_type(4))) float;

typedef const __attribute__((address_space(1))) void gv_t;
typedef __attribute__((address_space(3))) void lv_t;

// async 16B-per-lane global->LDS: lds dst is wave-uniform base, lane i lands at base+16*i
__device__ __forceinline__ void gl_lds16(const void* g, void* l) {
    __builtin_amdgcn_global_load_lds((gv_t*)g, (lv_t*)l, 16, 0, 0);
}

#define MFMA(a, b, c) __builtin_amdgcn_mfma_f32_16x16x32_bf16(a, b, c, 0, 0, 0)

__device__ __forceinline__ u16 f2bf(float f) {
    union { float f; unsigned u; } v; v.f = f;
    unsigned r = v.u + 0x7fffu + ((v.u >> 16) & 1u);  // RNE
    return (u16)(r >> 16);
}

__device__ __forceinline__ bf16x8 cvt8(const float* p) {
    float4 f0 = *(const float4*)p;
    float4 f1 = *(const float4*)(p + 4);
    union { bf16x8 v; u16 u[8]; } r;
    r.u[0] = f2bf(f0.x); r.u[1] = f2bf(f0.y); r.u[2] = f2bf(f0.z); r.u[3] = f2bf(f0.w);
    r.u[4] = f2bf(f1.x); r.u[5] = f2bf(f1.y); r.u[6] = f2bf(f1.z); r.u[7] = f2bf(f1.w);
    return r.v;
}

// ---- K1 prep (fused wprep + aT-gemm):
//   blocks 0..255:  wvw[f] = Wv[f,:]·Ww, kbv[f] = Wk[f,:]·bq; block 0 also cc = bv·Ww
//   blocks 256..263: aT[f][e] = bf16((Wk_bf[f,:]·Wq_bf[e,:])/16), weights
//   converted to bf16 in-kernel. ----
__global__ __launch_bounds__(256) void prep_kernel(
        const float* __restrict__ Wq, const float* __restrict__ Wk,
        const float* __restrict__ Wv, const float* __restrict__ Ww,
        const float* __restrict__ bq, const float* __restrict__ bv,
        u16* __restrict__ aTb, float* __restrict__ wvw,
        float* __restrict__ kbv, float* __restrict__ ccp) {
    __shared__ u16 bt[16384];   // 32KB fragment-major (gemm blocks only)
    int id = blockIdx.x, t = threadIdx.x;

    if (id < 256) {   // reduction blocks
        int f = id;
        float p = Wv[f * H + t] * Ww[t];
        float r = Wk[f * H + t] * bq[t];
        float c = (id == 0) ? bv[t] * Ww[t] : 0.f;
        for (int o = 32; o; o >>= 1) {
            p += __shfl_xor(p, o); r += __shfl_xor(r, o); c += __shfl_xor(c, o);
        }
        __shared__ float redp[4], redr[4], redc[4];
        int w = t >> 6, lane = t & 63;
        if (lane == 0) { redp[w] = p; redr[w] = r; redc[w] = c; }
        __syncthreads();
        if (t == 0) {
            wvw[f] = redp[0] + redp[1] + redp[2] + redp[3];
            kbv[f] = redr[0] + redr[1] + redr[2] + redr[3];
            if (f == 0) ccp[0] = redc[0] + redc[1] + redc[2] + redc[3];
        }
        return;
    }

    // gemm blocks: gid 0..7 -> 128x64 tile of aT (256x256), K=256
    int gid = id - 256;
    int mb = (gid >> 2) * 128, nb = (gid & 3) * 64;
    int w = t >> 6, lane = t & 63, l15 = lane & 15, quad = lane >> 4;

    {   // stage B = bf16(Wq rows nb..nb+63), fragment-major
        const float* src = Wq + (nb + w * 16 + l15) * H + quad * 8;
        #pragma unroll
        for (int ks = 0; ks < 8; ++ks)
            *(bf16x8*)(bt + (w * 8 + ks) * 512 + lane * 8) = cvt8(src + ks * 32);
    }

    bf16x8 a[2][8];
    #pragma unroll
    for (int mi = 0; mi < 2; ++mi) {
        const float* ab = Wk + (mb + w * 32 + mi * 16 + l15) * H + quad * 8;
        #pragma unroll
        for (int ks = 0; ks < 8; ++ks) a[mi][ks] = cvt8(ab + ks * 32);
    }
    __syncthreads();

    f32x4 acc[2][4] = {};
    #pragma unroll
    for (int ks = 0; ks < 8; ++ks)
        #pragma unroll
        for (int tt = 0; tt < 4; ++tt) {
            bf16x8 b = *(const bf16x8*)(bt + ((tt * 8 + ks) * 64 + lane) * 8);
            acc[0][tt] = MFMA(a[0][ks], b, acc[0][tt]);
            acc[1][tt] = MFMA(a[1][ks], b, acc[1][tt]);
        }

    #pragma unroll
    for (int mi = 0; mi < 2; ++mi) {
        int m = mb + w * 32 + mi * 16 + quad * 4;
        #pragma unroll
        for (int tt = 0; tt < 4; ++tt) {
            int n = nb + tt * 16 + l15;
            #pragma unroll
            for (int r2 = 0; r2 < 4; ++r2)
                aTb[(m + r2) * H + n] = f2bf(acc[mi][tt][r2] * 0.0625f);
        }
    }
}

// ---- K2 xt (fused cvtu + T-gemm, NO redundant x reads):
//   512 blocks, each owns 32 rows x ALL 256 cols of T. Each x row is read by
//   exactly one block (16 MB HBM total). B = aT streamed from global straight
//   into registers (128 KB, L2-hot) — no LDS, no barrier. ----
__global__ __launch_bounds__(256) void xt_kernel(
        const float* __restrict__ x, const u16* __restrict__ aTb,
        const float* __restrict__ wvw, const float* __restrict__ kbv,
        const float* __restrict__ ccp,
        u16* __restrict__ xbf, float2* __restrict__ uee, u16* __restrict__ Tbf) {
    int id = blockIdx.x, tid = threadIdx.x;
    int w = tid >> 6, lane = tid & 63, l15 = lane & 15, quad = lane >> 4;
    int rb = id * 32;   // this block's 32 rows

    // A: convert the 32 rows to bf16 fragments; uee dot partials ride along
    bf16x8 a[2][8];
    float s[2] = {0.f, 0.f}, d[2] = {0.f, 0.f};
    #pragma unroll
    for (int ks = 0; ks < 8; ++ks) {
        const float* wp = wvw + ks * 32 + quad * 8;
        const float* kp = kbv + ks * 32 + quad * 8;
        float4 w0 = *(const float4*)wp, w1 = *(const float4*)(wp + 4);
        float4 k0 = *(const float4*)kp, k1 = *(const float4*)(kp + 4);
        #pragma unroll
        for (int mi = 0; mi < 2; ++mi) {
            const float* xr = x + (size_t)(rb + mi * 16 + l15) * H + ks * 32 + quad * 8;
            float4 f0 = *(const float4*)xr;
            float4 f1 = *(const float4*)(xr + 4);
            union { bf16x8 v; u16 u[8]; } r;
            r.u[0] = f2bf(f0.x); r.u[1] = f2bf(f0.y); r.u[2] = f2bf(f0.z); r.u[3] = f2bf(f0.w);
            r.u[4] = f2bf(f1.x); r.u[5] = f2bf(f1.y); r.u[6] = f2bf(f1.z); r.u[7] = f2bf(f1.w);
            a[mi][ks] = r.v;
            s[mi] += f0.x * w0.x + f0.y * w0.y + f0.z * w0.z + f0.w * w0.w
                   + f1.x * w1.x + f1.y * w1.y + f1.z * w1.z + f1.w * w1.w;
            d[mi] += f0.x * k0.x + f0.y * k0.y + f0.z * k0.z + f0.w * k0.w
                   + f1.x * k1.x + f1.y * k1.y + f1.z * k1.z + f1.w * k1.w;
        }
    }

    if (w == 0) {   // wave 0 owns the xbf + uee writes for all 32 rows
        #pragma unroll
        for (int mi = 0; mi < 2; ++mi) {
            u16* xo = xbf + (size_t)(rb + mi * 16 + l15) * H + quad * 8;
            #pragma unroll
            for (int ks = 0; ks < 8; ++ks)
                *(bf16x8*)(xo + ks * 32) = a[mi][ks];
        }
        float cc = ccp[0];
        #pragma unroll
        for (int mi = 0; mi < 2; ++mi) {
            float ss = s[mi] + __shfl_xor(s[mi], 16); ss += __shfl_xor(ss, 32);
            float dd = d[mi] + __shfl_xor(d[mi], 16); dd += __shfl_xor(dd, 32);
            if (quad == 0) {
                float e = __expf(dd * 0.0625f);
                uee[rb + mi * 16 + l15] = make_float2(e * (ss + cc), e);
            }
        }
    }

    // B-streamed GEMM: 4 n-tiles per wave, acc finalized & stored per tile
    #pragma unroll 1
    for (int t = 0; t < 4; ++t) {
        int n = (w * 4 + t) * 16 + l15;
        const u16* bb = aTb + n * H + quad * 8;
        bf16x8 bfr[8];
        #pragma unroll
        for (int ks = 0; ks < 8; ++ks) bfr[ks] = *(const bf16x8*)(bb + ks * 32);
        f32x4 acc0 = {}, acc1 = {};
        #pragma unroll
        for (int ks = 0; ks < 8; ++ks) {
            acc0 = MFMA(a[0][ks], bfr[ks], acc0);
            acc1 = MFMA(a[1][ks], bfr[ks], acc1);
        }
        #pragma unroll
        for (int r2 = 0; r2 < 4; ++r2) {
            Tbf[(size_t)(rb + quad * 4 + r2) * H + n]      = f2bf(acc0[r2]);
            Tbf[(size_t)(rb + 16 + quad * 4 + r2) * H + n] = f2bf(acc1[r2]);
        }
    }
}

// ---- K3 attention: logit(n,m) = T[n]·x[m]; num += e^logit·(e·u)_m,
//      den += e^logit·e_m.  OCCUPANCY FIX (R3 profile: 12.5% MfmaUtil,
//      16.7% occupancy, everything stalled at 2 waves/SIMD): 512-thread
//      blocks (8 waves), each wave owns 32 q-rows (aq[2][8] = 64 VGPR,
//      was 128). Grid 512, LDS 64KB -> still 2 blocks/CU, but now
//      16 waves/CU = 4/SIMD = 50% occupancy cap; __launch_bounds__(512,4)
//      caps VGPR at 128. 64-key double-buffered tiles, t-outer/ks-inner,
//      setprio around MFMA. b in low 3 bits pins batch b -> XCD b. ----
__global__ __launch_bounds__(512, 4) void attn_kernel(
        const u16* __restrict__ T, const u16* __restrict__ xbf,
        const float2* __restrict__ uee,
        float* __restrict__ pnum, float* __restrict__ pden) {
    __shared__ u16 kt[32768];   // 2 x 32KB fragment-major 64-key tiles
    int tid = threadIdx.x;
    int id = blockIdx.x;
    int b = id & 7, rest = id >> 3;
    int qc = rest & 7, sp = rest >> 3;
    int w = tid >> 6, lane = tid & 63, l15 = lane & 15, quad = lane >> 4;
    int qb = qc * 256;

    // resident A fragments: 32 q-rows per wave (2 x 16)
    bf16x8 aq[2][8];
    {
        const u16* qbase = T + (size_t)(b * NB + qb + w * 32 + l15) * H + quad * 8;
        #pragma unroll
        for (int mi = 0; mi < 2; ++mi)
            #pragma unroll
            for (int ks = 0; ks < 8; ++ks)
                aq[mi][ks] = *(const bf16x8*)(qbase + mi * 16 * H + ks * 32);
    }

    const u16* xb = xbf + (size_t)b * NB * H;
    const float2* uep = uee + (size_t)b * NB;
    const int kb0 = sp * KSPAN;

    // staging: 32 chunks of 1KB per 64-key tile; wave w stages chunks w*4..w*4+3.
    // chunk c: t-group tg=c>>3, ks=c&7 -> key rows +tg*16+l15, cols ks*32+quad*8.
    #pragma unroll
    for (int j = 0; j < 4; ++j) {
        int c = w * 4 + j;
        gl_lds16(xb + (size_t)(kb0 + (c >> 3) * 16 + l15) * H + (c & 7) * 32 + quad * 8,
                 kt + c * 512);
    }
    __syncthreads();

    float ls[2][4] = {}, as_[2][4] = {};

    #pragma unroll 1
    for (int h = 0; h < NITER; ++h) {
        const u16* ktc = kt + (h & 1) * 16384;
        if (h + 1 < NITER) {   // stage next 64-key tile into the other buffer
            int kb64n = kb0 + (h + 1) * 64;
            u16* dst = kt + ((h & 1) ^ 1) * 16384;
            #pragma unroll
            for (int j = 0; j < 4; ++j) {
                int c = w * 4 + j;
                gl_lds16(xb + (size_t)(kb64n + (c >> 3) * 16 + l15) * H + (c & 7) * 32 + quad * 8,
                         dst + c * 512);
            }
        }
        int kb64 = kb0 + h * 64;
        float2 uv[4];
        #pragma unroll
        for (int t = 0; t < 4; ++t) uv[t] = uep[kb64 + t * 16 + l15];

        #pragma unroll
        for (int t = 0; t < 4; ++t) {
            f32x4 acc0 = {}, acc1 = {};
            __builtin_amdgcn_s_setprio(1);
            #pragma unroll
            for (int ks = 0; ks < 8; ++ks) {
                bf16x8 bfr = *(const bf16x8*)(ktc + ((t * 8 + ks) * 64 + lane) * 8);
                acc0 = MFMA(aq[0][ks], bfr, acc0);
                acc1 = MFMA(aq[1][ks], bfr, acc1);
            }
            __builtin_amdgcn_s_setprio(0);
            #pragma unroll
            for (int r = 0; r < 4; ++r) {
                float p0 = __expf(acc0[r]);
                float p1 = __expf(acc1[r]);
                as_[0][r] += p0 * uv[t].x;  ls[0][r] += p0 * uv[t].y;
                as_[1][r] += p1 * uv[t].x;  ls[1][r] += p1 * uv[t].y;
            }
        }
        __syncthreads();
    }

    // reduce over the 16 key-columns (l15)
    #pragma unroll
    for (int mi = 0; mi < 2; ++mi)
        #pragma unroll
        for (int r = 0; r < 4; ++r)
            for (int o = 1; o < 16; o <<= 1) {
                ls[mi][r]  += __shfl_xor(ls[mi][r], o);
                as_[mi][r] += __shfl_xor(as_[mi][r], o);
            }

    if (l15 == 0) {
        size_t base = (size_t)(sp * BATCH + b) * NB + qb + w * 32 + quad * 4;
        #pragma unroll
        for (int mi = 0; mi < 2; ++mi)
            #pragma unroll
            for (int r = 0; r < 4; ++r) {
                pnum[base + mi * 16 + r] = as_[mi][r];
                pden[base + mi * 16 + r] = ls[mi][r];
            }
    }
}

// ---- combine K-splits: out = sum(num)/sum(den) + bw ----
__global__ __launch_bounds__(256) void finalize_kernel(
        const float* __restrict__ pnum, const float* __restrict__ pden,
        const float* __restrict__ bw, float* __restrict__ out) {
    int i = blockIdx.x * 256 + threadIdx.x;   // i = b*NB + n
    float num = 0.f, den = 0.f;
    for (int sp = 0; sp < NSPLIT; ++sp) {
        num += pnum[sp * (BATCH * NB) + i];
        den += pden[sp * (BATCH * NB) + i];
    }
    out[i] = num / den + bw[0];
}

extern "C" void kernel_launch(void* const* d_in, const int* in_sizes, int n_in,
                              void* d_out, int out_size, void* d_ws, size_t ws_size,
                              hipStream_t stream) {
    (void)in_sizes; (void)n_in; (void)out_size; (void)ws_size;
    const float* x  = (const float*)d_in[0];
    const float* Wq = (const float*)d_in[1];
    const float* bq = (const float*)d_in[2];
    const float* Wk = (const float*)d_in[3];
    const float* bk = (const float*)d_in[4];  (void)bk;  // cancels in softmax
    const float* Wv = (const float*)d_in[5];
    const float* bv = (const float*)d_in[6];
    const float* Ww = (const float*)d_in[7];
    const float* bw = (const float*)d_in[8];
    float* out = (float*)d_out;

    u16* xbf = (u16*)d_ws;                     // 4194304 u16 (8 MB)
    u16* Tbf = xbf + 4194304;                  // 4194304 u16 (8 MB)
    u16* aTb = Tbf + 4194304;                  // 65536 u16
    float* wvw = (float*)(aTb + 65536);        // 256 f32
    float* kbv = wvw + 256;                    // 256 f32
    float* ccp = kbv + 256;                    // 4 f32 (1 used, keeps 8B align)
    float2* uee = (float2*)(ccp + 4);          // 16384 float2
    float* pnum = (float*)(uee + 16384);       // NSPLIT*16384 f32
    float* pden = pnum + NSPLIT * BATCH * NB;  // NSPLIT*16384 f32

    hipLaunchKernelGGL(prep_kernel, dim3(264), dim3(256), 0, stream,
                       Wq, Wk, Wv, Ww, bq, bv, aTb, wvw, kbv, ccp);
    hipLaunchKernelGGL(xt_kernel, dim3(512), dim3(256), 0, stream,
                       x, aTb, wvw, kbv, ccp, xbf, uee, Tbf);
    hipLaunchKernelGGL(attn_kernel, dim3(8 * 8 * NSPLIT), dim3(512), 0, stream,
                       Tbf, xbf, uee, pnum, pden);
    hipLaunchKernelGGL(finalize_kernel, dim3(64), dim3(256), 0, stream,
                       pnum, pden, bw, out);
}

// Round 5
// 133.399 us; speedup vs baseline: 1.1033x; 1.0441x over previous
//
#include <hip/hip_runtime.h>

#define H 256
#define NB 2048
#define BATCH 8
#define NSPLIT 8
#define KSPAN (NB / NSPLIT)   // 256 keys per split
#define NITER (KSPAN / 64)    // 4 double-buffered 64-key tiles

typedef unsigned short u16;
using bf16x8 = __attribute__((ext_vector_type(8))) __bf16;
using f32x4  = __attribute__((ext_vector_type(4))) float;

typedef const __attribute__((address_space(1))) void gv_t;
typedef __attribute__((address_space(3))) void lv_t;

// async 16B-per-lane global->LDS: lds dst is wave-uniform base, lane i lands at base+16*i
__device__ __forceinline__ void gl_lds16(const void* g, void* l) {
    __builtin_amdgcn_global_load_lds((gv_t*)g, (lv_t*)l, 16, 0, 0);
}

#define MFMA(a, b, c) __builtin_amdgcn_mfma_f32_16x16x32_bf16(a, b, c, 0, 0, 0)

__device__ __forceinline__ u16 f2bf(float f) {
    union { float f; unsigned u; } v; v.f = f;
    unsigned r = v.u + 0x7fffu + ((v.u >> 16) & 1u);  // RNE
    return (u16)(r >> 16);
}

__device__ __forceinline__ bf16x8 cvt8(const float* p) {
    float4 f0 = *(const float4*)p;
    float4 f1 = *(const float4*)(p + 4);
    union { bf16x8 v; u16 u[8]; } r;
    r.u[0] = f2bf(f0.x); r.u[1] = f2bf(f0.y); r.u[2] = f2bf(f0.z); r.u[3] = f2bf(f0.w);
    r.u[4] = f2bf(f1.x); r.u[5] = f2bf(f1.y); r.u[6] = f2bf(f1.z); r.u[7] = f2bf(f1.w);
    return r.v;
}

// ---- K1 prep (fused wprep + aT-gemm):
//   blocks 0..255:  wvw[f] = Wv[f,:]·Ww, kbv[f] = Wk[f,:]·bq; block 0 also cc = bv·Ww
//   blocks 256..263: aT[f][e] = bf16((Wk_bf[f,:]·Wq_bf[e,:])/16), weights
//   converted to bf16 in-kernel. ----
__global__ __launch_bounds__(256) void prep_kernel(
        const float* __restrict__ Wq, const float* __restrict__ Wk,
        const float* __restrict__ Wv, const float* __restrict__ Ww,
        const float* __restrict__ bq, const float* __restrict__ bv,
        u16* __restrict__ aTb, float* __restrict__ wvw,
        float* __restrict__ kbv, float* __restrict__ ccp) {
    __shared__ u16 bt[16384];   // 32KB fragment-major (gemm blocks only)
    int id = blockIdx.x, t = threadIdx.x;

    if (id < 256) {   // reduction blocks
        int f = id;
        float p = Wv[f * H + t] * Ww[t];
        float r = Wk[f * H + t] * bq[t];
        float c = (id == 0) ? bv[t] * Ww[t] : 0.f;
        for (int o = 32; o; o >>= 1) {
            p += __shfl_xor(p, o); r += __shfl_xor(r, o); c += __shfl_xor(c, o);
        }
        __shared__ float redp[4], redr[4], redc[4];
        int w = t >> 6, lane = t & 63;
        if (lane == 0) { redp[w] = p; redr[w] = r; redc[w] = c; }
        __syncthreads();
        if (t == 0) {
            wvw[f] = redp[0] + redp[1] + redp[2] + redp[3];
            kbv[f] = redr[0] + redr[1] + redr[2] + redr[3];
            if (f == 0) ccp[0] = redc[0] + redc[1] + redc[2] + redc[3];
        }
        return;
    }

    // gemm blocks: gid 0..7 -> 128x64 tile of aT (256x256), K=256
    int gid = id - 256;
    int mb = (gid >> 2) * 128, nb = (gid & 3) * 64;
    int w = t >> 6, lane = t & 63, l15 = lane & 15, quad = lane >> 4;

    {   // stage B = bf16(Wq rows nb..nb+63), fragment-major
        const float* src = Wq + (nb + w * 16 + l15) * H + quad * 8;
        #pragma unroll
        for (int ks = 0; ks < 8; ++ks)
            *(bf16x8*)(bt + (w * 8 + ks) * 512 + lane * 8) = cvt8(src + ks * 32);
    }

    bf16x8 a[2][8];
    #pragma unroll
    for (int mi = 0; mi < 2; ++mi) {
        const float* ab = Wk + (mb + w * 32 + mi * 16 + l15) * H + quad * 8;
        #pragma unroll
        for (int ks = 0; ks < 8; ++ks) a[mi][ks] = cvt8(ab + ks * 32);
    }
    __syncthreads();

    f32x4 acc[2][4] = {};
    #pragma unroll
    for (int ks = 0; ks < 8; ++ks)
        #pragma unroll
        for (int tt = 0; tt < 4; ++tt) {
            bf16x8 b = *(const bf16x8*)(bt + ((tt * 8 + ks) * 64 + lane) * 8);
            acc[0][tt] = MFMA(a[0][ks], b, acc[0][tt]);
            acc[1][tt] = MFMA(a[1][ks], b, acc[1][tt]);
        }

    #pragma unroll
    for (int mi = 0; mi < 2; ++mi) {
        int m = mb + w * 32 + mi * 16 + quad * 4;
        #pragma unroll
        for (int tt = 0; tt < 4; ++tt) {
            int n = nb + tt * 16 + l15;
            #pragma unroll
            for (int r2 = 0; r2 < 4; ++r2)
                aTb[(m + r2) * H + n] = f2bf(acc[mi][tt][r2] * 0.0625f);
        }
    }
}

// ---- K2 xt (fused cvtu + T-gemm, NO redundant x reads):
//   512 blocks, each owns 32 rows x ALL 256 cols of T. Each x row is read by
//   exactly one block (16 MB HBM total). B = aT streamed from global straight
//   into registers (128 KB, L2/L3-hot) — no LDS, no barrier. ----
__global__ __launch_bounds__(256) void xt_kernel(
        const float* __restrict__ x, const u16* __restrict__ aTb,
        const float* __restrict__ wvw, const float* __restrict__ kbv,
        const float* __restrict__ ccp,
        u16* __restrict__ xbf, float2* __restrict__ uee, u16* __restrict__ Tbf) {
    int id = blockIdx.x, tid = threadIdx.x;
    int w = tid >> 6, lane = tid & 63, l15 = lane & 15, quad = lane >> 4;
    int rb = id * 32;   // this block's 32 rows

    // A: convert the 32 rows to bf16 fragments; uee dot partials ride along
    bf16x8 a[2][8];
    float s[2] = {0.f, 0.f}, d[2] = {0.f, 0.f};
    #pragma unroll
    for (int ks = 0; ks < 8; ++ks) {
        const float* wp = wvw + ks * 32 + quad * 8;
        const float* kp = kbv + ks * 32 + quad * 8;
        float4 w0 = *(const float4*)wp, w1 = *(const float4*)(wp + 4);
        float4 k0 = *(const float4*)kp, k1 = *(const float4*)(kp + 4);
        #pragma unroll
        for (int mi = 0; mi < 2; ++mi) {
            const float* xr = x + (size_t)(rb + mi * 16 + l15) * H + ks * 32 + quad * 8;
            float4 f0 = *(const float4*)xr;
            float4 f1 = *(const float4*)(xr + 4);
            union { bf16x8 v; u16 u[8]; } r;
            r.u[0] = f2bf(f0.x); r.u[1] = f2bf(f0.y); r.u[2] = f2bf(f0.z); r.u[3] = f2bf(f0.w);
            r.u[4] = f2bf(f1.x); r.u[5] = f2bf(f1.y); r.u[6] = f2bf(f1.z); r.u[7] = f2bf(f1.w);
            a[mi][ks] = r.v;
            s[mi] += f0.x * w0.x + f0.y * w0.y + f0.z * w0.z + f0.w * w0.w
                   + f1.x * w1.x + f1.y * w1.y + f1.z * w1.z + f1.w * w1.w;
            d[mi] += f0.x * k0.x + f0.y * k0.y + f0.z * k0.z + f0.w * k0.w
                   + f1.x * k1.x + f1.y * k1.y + f1.z * k1.z + f1.w * k1.w;
        }
    }

    if (w == 0) {   // wave 0 owns the xbf + uee writes for all 32 rows
        #pragma unroll
        for (int mi = 0; mi < 2; ++mi) {
            u16* xo = xbf + (size_t)(rb + mi * 16 + l15) * H + quad * 8;
            #pragma unroll
            for (int ks = 0; ks < 8; ++ks)
                *(bf16x8*)(xo + ks * 32) = a[mi][ks];
        }
        float cc = ccp[0];
        #pragma unroll
        for (int mi = 0; mi < 2; ++mi) {
            float ss = s[mi] + __shfl_xor(s[mi], 16); ss += __shfl_xor(ss, 32);
            float dd = d[mi] + __shfl_xor(d[mi], 16); dd += __shfl_xor(dd, 32);
            if (quad == 0) {
                float e = __expf(dd * 0.0625f);
                uee[rb + mi * 16 + l15] = make_float2(e * (ss + cc), e);
            }
        }
    }

    // B-streamed GEMM: 4 n-tiles per wave, acc finalized & stored per tile
    #pragma unroll 1
    for (int t = 0; t < 4; ++t) {
        int n = (w * 4 + t) * 16 + l15;
        const u16* bb = aTb + n * H + quad * 8;
        bf16x8 bfr[8];
        #pragma unroll
        for (int ks = 0; ks < 8; ++ks) bfr[ks] = *(const bf16x8*)(bb + ks * 32);
        f32x4 acc0 = {}, acc1 = {};
        #pragma unroll
        for (int ks = 0; ks < 8; ++ks) {
            acc0 = MFMA(a[0][ks], bfr[ks], acc0);
            acc1 = MFMA(a[1][ks], bfr[ks], acc1);
        }
        #pragma unroll
        for (int r2 = 0; r2 < 4; ++r2) {
            Tbf[(size_t)(rb + quad * 4 + r2) * H + n]      = f2bf(acc0[r2]);
            Tbf[(size_t)(rb + 16 + quad * 4 + r2) * H + n] = f2bf(acc1[r2]);
        }
    }
}

// ---- K3 attention: REVERTED to the best-measured structure (Round-1,
//      126.8 total): 256 threads, 4 waves, M=4 (64 q-rows/wave -> each
//      ds_read_b128 B-fragment feeds 4 MFMAs, halving LDS-pipe pressure vs
//      M=2 — R4's 512t/M=2 variant was ~2x slower), 64-key double-buffered
//      tiles, t-outer/ks-inner, one barrier per tile. setprio around the
//      MFMA cluster (neutral-to-positive per R2). Grid 512 = 2 blocks/CU;
//      b in low 3 bits pins batch b -> XCD b. ----
__global__ __launch_bounds__(256, 2) void attn_kernel(
        const u16* __restrict__ T, const u16* __restrict__ xbf,
        const float2* __restrict__ uee,
        float* __restrict__ pnum, float* __restrict__ pden) {
    __shared__ u16 kt[32768];   // 2 x 32KB fragment-major 64-key tiles
    int tid = threadIdx.x;
    int id = blockIdx.x;
    int b = id & 7, rest = id >> 3;
    int qc = rest & 7, sp = rest >> 3;
    int w = tid >> 6, lane = tid & 63, l15 = lane & 15, quad = lane >> 4;
    int qb = qc * 256;

    // resident A fragments: 64 q-rows per wave (4 x 16)
    bf16x8 aq[4][8];
    {
        const u16* qbase = T + (size_t)(b * NB + qb + w * 64 + l15) * H + quad * 8;
        #pragma unroll
        for (int mi = 0; mi < 4; ++mi)
            #pragma unroll
            for (int ks = 0; ks < 8; ++ks)
                aq[mi][ks] = *(const bf16x8*)(qbase + mi * 16 * H + ks * 32);
    }

    const u16* xb = xbf + (size_t)b * NB * H;
    const float2* uep = uee + (size_t)b * NB;
    const int kb0 = sp * KSPAN;

    // wave w stages t-group w (16 keys, 8 ks-chunks of 1KB) of each 64-key tile
    const u16* gsrc = xb + (size_t)(kb0 + w * 16 + l15) * H + quad * 8;
    #pragma unroll
    for (int j = 0; j < 8; ++j)
        gl_lds16(gsrc + j * 32, kt + (w * 8 + j) * 512);
    __syncthreads();

    float ls[4][4] = {}, as_[4][4] = {};

    #pragma unroll 1
    for (int h = 0; h < NITER; ++h) {
        const u16* ktc = kt + (h & 1) * 16384;
        if (h + 1 < NITER) {   // stage next 64-key tile into the other buffer
            u16* dst = kt + ((h & 1) ^ 1) * 16384;
            const u16* g2 = gsrc + (size_t)(h + 1) * 64 * H;
            #pragma unroll
            for (int j = 0; j < 8; ++j)
                gl_lds16(g2 + j * 32, dst + (w * 8 + j) * 512);
        }
        int kb64 = kb0 + h * 64;
        float2 uv[4];
        #pragma unroll
        for (int t = 0; t < 4; ++t) uv[t] = uep[kb64 + t * 16 + l15];

        #pragma unroll
        for (int t = 0; t < 4; ++t) {
            f32x4 acc[4] = {};
            __builtin_amdgcn_s_setprio(1);
            #pragma unroll
            for (int ks = 0; ks < 8; ++ks) {
                bf16x8 bfr = *(const bf16x8*)(ktc + ((t * 8 + ks) * 64 + lane) * 8);
                acc[0] = MFMA(aq[0][ks], bfr, acc[0]);
                acc[1] = MFMA(aq[1][ks], bfr, acc[1]);
                acc[2] = MFMA(aq[2][ks], bfr, acc[2]);
                acc[3] = MFMA(aq[3][ks], bfr, acc[3]);
            }
            __builtin_amdgcn_s_setprio(0);
            #pragma unroll
            for (int mi = 0; mi < 4; ++mi)
                #pragma unroll
                for (int r = 0; r < 4; ++r) {
                    float p = __expf(acc[mi][r]);
                    as_[mi][r] += p * uv[t].x;
                    ls[mi][r]  += p * uv[t].y;
                }
        }
        __syncthreads();
    }

    // reduce over the 16 key-columns (l15)
    #pragma unroll
    for (int mi = 0; mi < 4; ++mi)
        #pragma unroll
        for (int r = 0; r < 4; ++r)
            for (int o = 1; o < 16; o <<= 1) {
                ls[mi][r]  += __shfl_xor(ls[mi][r], o);
                as_[mi][r] += __shfl_xor(as_[mi][r], o);
            }

    if (l15 == 0) {
        size_t base = (size_t)(sp * BATCH + b) * NB + qb + w * 64 + quad * 4;
        #pragma unroll
        for (int mi = 0; mi < 4; ++mi)
            #pragma unroll
            for (int r = 0; r < 4; ++r) {
                pnum[base + mi * 16 + r] = as_[mi][r];
                pden[base + mi * 16 + r] = ls[mi][r];
            }
    }
}

// ---- combine K-splits: out = sum(num)/sum(den) + bw ----
__global__ __launch_bounds__(256) void finalize_kernel(
        const float* __restrict__ pnum, const float* __restrict__ pden,
        const float* __restrict__ bw, float* __restrict__ out) {
    int i = blockIdx.x * 256 + threadIdx.x;   // i = b*NB + n
    float num = 0.f, den = 0.f;
    for (int sp = 0; sp < NSPLIT; ++sp) {
        num += pnum[sp * (BATCH * NB) + i];
        den += pden[sp * (BATCH * NB) + i];
    }
    out[i] = num / den + bw[0];
}

extern "C" void kernel_launch(void* const* d_in, const int* in_sizes, int n_in,
                              void* d_out, int out_size, void* d_ws, size_t ws_size,
                              hipStream_t stream) {
    (void)in_sizes; (void)n_in; (void)out_size; (void)ws_size;
    const float* x  = (const float*)d_in[0];
    const float* Wq = (const float*)d_in[1];
    const float* bq = (const float*)d_in[2];
    const float* Wk = (const float*)d_in[3];
    const float* bk = (const float*)d_in[4];  (void)bk;  // cancels in softmax
    const float* Wv = (const float*)d_in[5];
    const float* bv = (const float*)d_in[6];
    const float* Ww = (const float*)d_in[7];
    const float* bw = (const float*)d_in[8];
    float* out = (float*)d_out;

    u16* xbf = (u16*)d_ws;                     // 4194304 u16 (8 MB)
    u16* Tbf = xbf + 4194304;                  // 4194304 u16 (8 MB)
    u16* aTb = Tbf + 4194304;                  // 65536 u16
    float* wvw = (float*)(aTb + 65536);        // 256 f32
    float* kbv = wvw + 256;                    // 256 f32
    float* ccp = kbv + 256;                    // 4 f32 (1 used, keeps 8B align)
    float2* uee = (float2*)(ccp + 4);          // 16384 float2
    float* pnum = (float*)(uee + 16384);       // NSPLIT*16384 f32
    float* pden = pnum + NSPLIT * BATCH * NB;  // NSPLIT*16384 f32

    hipLaunchKernelGGL(prep_kernel, dim3(264), dim3(256), 0, stream,
                       Wq, Wk, Wv, Ww, bq, bv, aTb, wvw, kbv, ccp);
    hipLaunchKernelGGL(xt_kernel, dim3(512), dim3(256), 0, stream,
                       x, aTb, wvw, kbv, ccp, xbf, uee, Tbf);
    hipLaunchKernelGGL(attn_kernel, dim3(8 * 8 * NSPLIT), dim3(256), 0, stream,
                       Tbf, xbf, uee, pnum, pden);
    hipLaunchKernelGGL(finalize_kernel, dim3(64), dim3(256), 0, stream,
                       pnum, pden, bw, out);
}

// Round 6
// 131.732 us; speedup vs baseline: 1.1173x; 1.0127x over previous
//
#include <hip/hip_runtime.h>

#define H 256
#define NB 2048
#define BATCH 8
#define NSPLIT 16
#define KSPAN (NB / NSPLIT)   // 128 keys per split
#define NHALF (KSPAN / 32)    // 4 double-buffered 32-key tiles

typedef unsigned short u16;
using bf16x8 = __attribute__((ext_vector_type(8))) __bf16;
using f32x4  = __attribute__((ext_vector_type(4))) float;

typedef const __attribute__((address_space(1))) void gv_t;
typedef __attribute__((address_space(3))) void lv_t;

// async 16B-per-lane global->LDS: lds dst is wave-uniform base, lane i lands at base+16*i
__device__ __forceinline__ void gl_lds16(const void* g, void* l) {
    __builtin_amdgcn_global_load_lds((gv_t*)g, (lv_t*)l, 16, 0, 0);
}

#define MFMA(a, b, c) __builtin_amdgcn_mfma_f32_16x16x32_bf16(a, b, c, 0, 0, 0)

__device__ __forceinline__ u16 f2bf(float f) {
    union { float f; unsigned u; } v; v.f = f;
    unsigned r = v.u + 0x7fffu + ((v.u >> 16) & 1u);  // RNE
    return (u16)(r >> 16);
}

// ---- coalesced weight prep (one block per row f):
//   wqb/wkb = bf16(Wq/Wk) row-major; wvw[f] = Wv[f,:]·Ww; kbv[f] = Wk[f,:]·bq ----
__global__ __launch_bounds__(256) void wprep_kernel(
        const float* __restrict__ Wq, const float* __restrict__ Wk,
        const float* __restrict__ Wv, const float* __restrict__ Ww,
        const float* __restrict__ bq,
        u16* __restrict__ wqb, u16* __restrict__ wkb,
        float* __restrict__ wvw, float* __restrict__ kbv) {
    int f = blockIdx.x, t = threadIdx.x;
    float wq = Wq[f * H + t];
    wqb[f * H + t] = f2bf(wq);
    float wk = Wk[f * H + t];
    wkb[f * H + t] = f2bf(wk);
    float p = Wv[f * H + t] * Ww[t];
    float r = wk * bq[t];
    for (int o = 32; o; o >>= 1) { p += __shfl_xor(p, o); r += __shfl_xor(r, o); }
    __shared__ float redp[4], redr[4];
    int w = t >> 6, lane = t & 63;
    if (lane == 0) { redp[w] = p; redr[w] = r; }
    __syncthreads();
    if (t == 0) {
        wvw[f] = redp[0] + redp[1] + redp[2] + redp[3];
        kbv[f] = redr[0] + redr[1] + redr[2] + redr[3];
    }
}

// ---- x -> bf16; per-row: u = x·wvw + bv·Ww, d = (x·kbv)/16, e = exp(d);
//      store uee[row] = {e*u, e}.  One wave per row. ----
__global__ __launch_bounds__(256) void cvtu_kernel(
        const float* __restrict__ x, const float* __restrict__ wvw,
        const float* __restrict__ kbv, const float* __restrict__ bv,
        const float* __restrict__ Ww,
        u16* __restrict__ xbf, float2* __restrict__ uee) {
    int lane = threadIdx.x & 63;
    int row  = blockIdx.x * 4 + (threadIdx.x >> 6);
    float4 xv = *(const float4*)(x + row * H + lane * 4);
    ushort4 o;
    o.x = f2bf(xv.x); o.y = f2bf(xv.y); o.z = f2bf(xv.z); o.w = f2bf(xv.w);
    *(ushort4*)(xbf + row * H + lane * 4) = o;
    float4 wv = *(const float4*)(wvw + lane * 4);
    float s = xv.x * wv.x + xv.y * wv.y + xv.z * wv.z + xv.w * wv.w;
    float4 kv = *(const float4*)(kbv + lane * 4);
    float d = xv.x * kv.x + xv.y * kv.y + xv.z * kv.z + xv.w * kv.w;
    float4 bvv = *(const float4*)(bv + lane * 4);
    float4 www = *(const float4*)(Ww + lane * 4);
    float c = bvv.x * www.x + bvv.y * www.y + bvv.z * www.z + bvv.w * www.w;
    for (int o2 = 32; o2; o2 >>= 1) {
        s += __shfl_xor(s, o2); d += __shfl_xor(d, o2); c += __shfl_xor(c, o2);
    }
    if (lane == 0) {
        float e = __expf(d * 0.0625f);
        uee[row] = make_float2(e * (s + c), e);
    }
}

// ---- generic C = (A @ B^T) * scale, bf16 in/out, MFMA 16x16x32, M=2/wave. ----
__global__ __launch_bounds__(256) void gemm_bt_kernel(
        const u16* __restrict__ A, const u16* __restrict__ B,
        u16* __restrict__ C, float scale) {
    __shared__ u16 bt[16384];   // 32KB fragment-major
    int tid = threadIdx.x;
    int mb = blockIdx.x * 128, nb = blockIdx.y * 64;
    int w = tid >> 6, lane = tid & 63;
    int l15 = lane & 15, quad = lane >> 4;

    {   // wave w stages t=w, ks=0..7
        const u16* gsrc = B + (nb + w * 16 + l15) * H + quad * 8;
        for (int ks = 0; ks < 8; ++ks)
            gl_lds16(gsrc + ks * 32, bt + (w * 8 + ks) * 512);
    }

    bf16x8 a[2][8];
    for (int mi = 0; mi < 2; ++mi) {
        const u16* abase = A + (size_t)(mb + w * 32 + mi * 16 + l15) * H + quad * 8;
        for (int ks = 0; ks < 8; ++ks) a[mi][ks] = *(const bf16x8*)(abase + ks * 32);
    }
    __syncthreads();

    f32x4 acc[2][4] = {};
    for (int ks = 0; ks < 8; ++ks)
        for (int t = 0; t < 4; ++t) {
            bf16x8 b = *(const bf16x8*)(bt + ((t * 8 + ks) * 64 + lane) * 8);
            acc[0][t] = MFMA(a[0][ks], b, acc[0][t]);
            acc[1][t] = MFMA(a[1][ks], b, acc[1][t]);
        }

    for (int mi = 0; mi < 2; ++mi) {
        int m = mb + w * 32 + mi * 16 + quad * 4;
        for (int t = 0; t < 4; ++t) {
            int n = nb + t * 16 + l15;
            for (int r = 0; r < 4; ++r)
                C[(size_t)(m + r) * H + n] = f2bf(acc[mi][t][r] * scale);
        }
    }
}

// ---- attention: logit(n,m) = T[n]·x[m]; num += e^logit·(e·u)_m, den += e^logit·e_m.
//      M=4 (64 q-rows/wave: each ds_read_b128 B-fragment feeds 4 MFMAs — LDS-
//      invariant-optimal at the 256-reg/wave VGPR cap).  BLOCK-TURNOVER FIX:
//      NSPLIT=16, 32-key double-buffered tiles (LDS 32KB), grid 1024 = 4 queued
//      blocks/CU (2 resident, VGPR-capped) -> successor blocks cover each
//      block's prologue (32 global b128 aq loads), barrier drains and epilogue;
//      per-block serial path halves. t-outer/ks-inner + setprio around MFMA.
//      b in low 3 bits pins batch b -> XCD b. ----
__global__ __launch_bounds__(256, 2) void attn_kernel(
        const u16* __restrict__ T, const u16* __restrict__ xbf,
        const float2* __restrict__ uee,
        float* __restrict__ pnum, float* __restrict__ pden) {
    __shared__ u16 kt[16384];   // 2 x 16KB fragment-major 32-key tiles
    int tid = threadIdx.x;
    int id = blockIdx.x;
    int b = id & 7, rest = id >> 3;
    int qc = rest & 7, sp = rest >> 3;   // sp 0..15
    int w = tid >> 6, lane = tid & 63, l15 = lane & 15, quad = lane >> 4;
    int qb = qc * 256;

    // resident A fragments: 64 q-rows per wave (4 x 16)
    bf16x8 aq[4][8];
    {
        const u16* qbase = T + (size_t)(b * NB + qb + w * 64 + l15) * H + quad * 8;
        #pragma unroll
        for (int mi = 0; mi < 4; ++mi)
            #pragma unroll
            for (int ks = 0; ks < 8; ++ks)
                aq[mi][ks] = *(const bf16x8*)(qbase + mi * 16 * H + ks * 32);
    }

    const u16* xb = xbf + (size_t)b * NB * H;
    const float2* uep = uee + (size_t)b * NB;
    const int kb0 = sp * KSPAN;
    int c0 = w * 4;   // wave w stages chunks c0..c0+3 of the 16-chunk tile

    // stage tile 0 (32 keys = 2 t-groups x 8 ks-chunks of 1KB)
    #pragma unroll
    for (int j = 0; j < 4; ++j) {
        int c = c0 + j;
        gl_lds16(xb + (size_t)(kb0 + (c >> 3) * 16 + l15) * H + (c & 7) * 32 + quad * 8,
                 kt + c * 512);
    }
    __syncthreads();

    float ls[4][4] = {}, as_[4][4] = {};

    #pragma unroll 1
    for (int h = 0; h < NHALF; ++h) {
        const u16* ktc = kt + (h & 1) * 8192;
        if (h + 1 < NHALF) {   // stage next 32-key tile into the other buffer
            int kb32n = kb0 + (h + 1) * 32;
            u16* dst = kt + ((h & 1) ^ 1) * 8192;
            #pragma unroll
            for (int j = 0; j < 4; ++j) {
                int c = c0 + j;
                gl_lds16(xb + (size_t)(kb32n + (c >> 3) * 16 + l15) * H + (c & 7) * 32 + quad * 8,
                         dst + c * 512);
            }
        }
        int kb32 = kb0 + h * 32;
        float2 uv0 = uep[kb32 + l15];
        float2 uv1 = uep[kb32 + 16 + l15];

        #pragma unroll
        for (int t = 0; t < 2; ++t) {
            float2 uv = t ? uv1 : uv0;
            f32x4 acc[4] = {};
            __builtin_amdgcn_s_setprio(1);
            #pragma unroll
            for (int ks = 0; ks < 8; ++ks) {
                bf16x8 bfr = *(const bf16x8*)(ktc + ((t * 8 + ks) * 64 + lane) * 8);
                acc[0] = MFMA(aq[0][ks], bfr, acc[0]);
                acc[1] = MFMA(aq[1][ks], bfr, acc[1]);
                acc[2] = MFMA(aq[2][ks], bfr, acc[2]);
                acc[3] = MFMA(aq[3][ks], bfr, acc[3]);
            }
            __builtin_amdgcn_s_setprio(0);
            #pragma unroll
            for (int mi = 0; mi < 4; ++mi)
                #pragma unroll
                for (int r = 0; r < 4; ++r) {
                    float p = __expf(acc[mi][r]);
                    as_[mi][r] += p * uv.x;
                    ls[mi][r]  += p * uv.y;
                }
        }
        __syncthreads();
    }

    // reduce over the 16 key-columns (l15)
    #pragma unroll
    for (int mi = 0; mi < 4; ++mi)
        #pragma unroll
        for (int r = 0; r < 4; ++r)
            for (int o = 1; o < 16; o <<= 1) {
                ls[mi][r]  += __shfl_xor(ls[mi][r], o);
                as_[mi][r] += __shfl_xor(as_[mi][r], o);
            }

    if (l15 == 0) {
        size_t base = (size_t)(sp * BATCH + b) * NB + qb + w * 64 + quad * 4;
        #pragma unroll
        for (int mi = 0; mi < 4; ++mi)
            #pragma unroll
            for (int r = 0; r < 4; ++r) {
                pnum[base + mi * 16 + r] = as_[mi][r];
                pden[base + mi * 16 + r] = ls[mi][r];
            }
    }
}

// ---- combine K-splits: out = sum(num)/sum(den) + bw ----
__global__ __launch_bounds__(256) void finalize_kernel(
        const float* __restrict__ pnum, const float* __restrict__ pden,
        const float* __restrict__ bw, float* __restrict__ out) {
    int i = blockIdx.x * 256 + threadIdx.x;   // i = b*NB + n
    float num = 0.f, den = 0.f;
    for (int sp = 0; sp < NSPLIT; ++sp) {
        num += pnum[sp * (BATCH * NB) + i];
        den += pden[sp * (BATCH * NB) + i];
    }
    out[i] = num / den + bw[0];
}

extern "C" void kernel_launch(void* const* d_in, const int* in_sizes, int n_in,
                              void* d_out, int out_size, void* d_ws, size_t ws_size,
                              hipStream_t stream) {
    (void)in_sizes; (void)n_in; (void)out_size; (void)ws_size;
    const float* x  = (const float*)d_in[0];
    const float* Wq = (const float*)d_in[1];
    const float* bq = (const float*)d_in[2];
    const float* Wk = (const float*)d_in[3];
    const float* bk = (const float*)d_in[4];  (void)bk;  // cancels in softmax
    const float* Wv = (const float*)d_in[5];
    const float* bv = (const float*)d_in[6];
    const float* Ww = (const float*)d_in[7];
    const float* bw = (const float*)d_in[8];
    float* out = (float*)d_out;

    u16* xbf = (u16*)d_ws;                     // 4194304 u16 (8 MB)
    u16* Tbf = xbf + 4194304;                  // 4194304 u16 (8 MB)
    u16* aTb = Tbf + 4194304;                  // 65536 u16
    u16* wqb = aTb + 65536;                    // 65536 u16
    u16* wkb = wqb + 65536;                    // 65536 u16
    float* wvw = (float*)(wkb + 65536);        // 256 f32
    float* kbv = wvw + 256;                    // 256 f32
    float2* uee = (float2*)(kbv + 256);        // 16384 float2
    float* pnum = (float*)(uee + 16384);       // NSPLIT*16384 f32
    float* pden = pnum + NSPLIT * BATCH * NB;  // NSPLIT*16384 f32

    hipLaunchKernelGGL(wprep_kernel, dim3(256), dim3(256), 0, stream,
                       Wq, Wk, Wv, Ww, bq, wqb, wkb, wvw, kbv);
    // aT[f][e] = (Wk[f,:]·Wq[e,:])/16
    hipLaunchKernelGGL(gemm_bt_kernel, dim3(2, 4), dim3(256), 0, stream,
                       wkb, wqb, aTb, 0.0625f);
    hipLaunchKernelGGL(cvtu_kernel, dim3(4096), dim3(256), 0, stream,
                       x, wvw, kbv, bv, Ww, xbf, uee);
    // T = xbf @ aT^T (aTb rows are B-operand rows)
    hipLaunchKernelGGL(gemm_bt_kernel, dim3(128, 4), dim3(256), 0, stream,
                       xbf, aTb, Tbf, 1.0f);
    hipLaunchKernelGGL(attn_kernel, dim3(8 * 8 * NSPLIT), dim3(256), 0, stream,
                       Tbf, xbf, uee, pnum, pden);
    hipLaunchKernelGGL(finalize_kernel, dim3(64), dim3(256), 0, stream,
                       pnum, pden, bw, out);
}